// Round 5
// baseline (349.201 us; speedup 1.0000x reference)
//
#include <hip/hip_runtime.h>
#include <math.h>

// Problem constants: B=2, S=2048, E=1024, NH=16, hd=64, T=1 (seq = S)
#define BB 2
#define SS 2048
#define EE 1024
#define NHH 16
#define HD 64
#define HD2 32

typedef __attribute__((ext_vector_type(8))) short bf16x8;   // 8 bf16 = 4 VGPRs
typedef __attribute__((ext_vector_type(4))) float f32x4;    // MFMA accumulator

// ---- cheap split-bf16 helpers (RTZ hi + RTZ lo residual; hi+lo ~ 2^-16 rel) ----
// pk_hi(a,b): packs bf16_rtz(a) into low16, bf16_rtz(b) into high16 — 1 v_perm_b32.
static __device__ __forceinline__ unsigned pk_hi(float a, float b) {
    union { float f; unsigned u; } x, y; x.f = a; y.f = b;
    return __builtin_amdgcn_perm(y.u, x.u, 0x07060302u);
}
static __device__ __forceinline__ float hi_trunc(float a) {
    union { float f; unsigned u; } x; x.f = a; x.u &= 0xffff0000u;
    return x.f;
}
// packed = hi | lo<<16 for one value (epilogue format)
static __device__ __forceinline__ unsigned split_pack(float o) {
    return pk_hi(o, o - hi_trunc(o));
}

// ---------------- kernel 1: RoPE cos/sin tables ----------------
__global__ __launch_bounds__(256) void rope_table_k(float* __restrict__ ct,
                                                    float* __restrict__ st) {
    int idx = blockIdx.x * 256 + threadIdx.x;   // idx = s*32 + p
    if (idx >= SS * HD2) return;
    int s = idx >> 5, p = idx & 31;
    double inv = pow(10000.0, -(double)(2 * p) / 64.0);
    double ang = (double)s * inv;
    ct[idx] = (float)cos(ang);
    st[idx] = (float)sin(ang);
}

// ---------------- kernel 2: QKV GEMM (split-bf16 MFMA) + bias + RoPE ------
// C = X @ W^T + bias. 128x128 tile, BK=32, 4 waves each 64x64 (4x4 of 16x16).
// Q is pre-scaled by 0.125*log2(e) so attention can use exp2 directly.
// launch_bounds(256,3): grid gives 3 blocks/CU, LDS allows 5 — ask the
// allocator for 3 waves/EU (VGPR<=170) so all 3 blocks are resident.
__global__ __launch_bounds__(256, 3) void qkv_mfma_k(
    const float* __restrict__ X, const float* __restrict__ W,
    const float* __restrict__ bias,
    const float* __restrict__ ct, const float* __restrict__ st,
    unsigned short* __restrict__ Qg, unsigned short* __restrict__ Kg,
    unsigned short* __restrict__ Vg)
{
    __shared__ __align__(16) unsigned short Alds[8192];   // 16 KB
    __shared__ __align__(16) unsigned short Blds[8192];   // 16 KB

    const int tid  = threadIdx.x;
    const int wave = tid >> 6;
    const int lane = tid & 63;
    const int quad = lane >> 4;
    const int l15  = lane & 15;
    const int m0   = blockIdx.y * 128;
    const int n0b  = blockIdx.x * 128;

    const int r  = tid >> 1;
    const int ks = (tid & 1) * 16;
    const int q0s = ks >> 3;
    const int grp_s = r >> 4;
    const int l15s  = r & 15;

    const float* ap = X + (size_t)(m0 + r) * EE + ks;
    const float* bp = W + (size_t)(n0b + r) * EE + ks;

    f32x4 acc[4][4];
#pragma unroll
    for (int mc = 0; mc < 4; mc++)
#pragma unroll
        for (int nc = 0; nc < 4; nc++) acc[mc][nc] = (f32x4){0.f, 0.f, 0.f, 0.f};

    float4 a[4], bb[4];
#pragma unroll
    for (int i = 0; i < 4; i++) {
        a[i]  = *(const float4*)(ap + i * 4);
        bb[i] = *(const float4*)(bp + i * 4);
    }

    const int mg = (wave >> 1) * 4;
    const int ng = (wave & 1) * 4;

    for (int kt = 0; kt < EE / 32; kt++) {
        __syncthreads();
        // ---- convert (RTZ hi/lo, perm-packed) + write staged tile ----
#pragma unroll
        for (int half = 0; half < 2; half++) {
            int q = q0s + half;
            const float* fa = (const float*)&a[half * 2];
            const float* fb = (const float*)&bb[half * 2];
            unsigned hia[4], loa[4], hib[4], lob[4];
#pragma unroll
            for (int jj = 0; jj < 4; jj++) {
                float pa0 = fa[2 * jj], pa1 = fa[2 * jj + 1];
                hia[jj] = pk_hi(pa0, pa1);
                loa[jj] = pk_hi(pa0 - hi_trunc(pa0), pa1 - hi_trunc(pa1));
                float pb0 = fb[2 * jj], pb1 = fb[2 * jj + 1];
                hib[jj] = pk_hi(pb0, pb1);
                lob[jj] = pk_hi(pb0 - hi_trunc(pb0), pb1 - hi_trunc(pb1));
            }
            int ehi = ((grp_s * 2 + 0) * 4 + q) * 128 + l15s * 8;
            int elo = ((grp_s * 2 + 1) * 4 + q) * 128 + l15s * 8;
            *(uint4*)(Alds + ehi) = make_uint4(hia[0], hia[1], hia[2], hia[3]);
            *(uint4*)(Alds + elo) = make_uint4(loa[0], loa[1], loa[2], loa[3]);
            *(uint4*)(Blds + ehi) = make_uint4(hib[0], hib[1], hib[2], hib[3]);
            *(uint4*)(Blds + elo) = make_uint4(lob[0], lob[1], lob[2], lob[3]);
        }
        __syncthreads();

        if (kt < EE / 32 - 1) {
            ap += 32; bp += 32;
#pragma unroll
            for (int i = 0; i < 4; i++) {
                a[i]  = *(const float4*)(ap + i * 4);
                bb[i] = *(const float4*)(bp + i * 4);
            }
        }

        bf16x8 Ah[4], Al[4], Bh[4], Bl[4];
#pragma unroll
        for (int mc = 0; mc < 4; mc++) {
            int base = ((mg + mc) * 8 + quad) * 128 + l15 * 8;
            Ah[mc] = *(const bf16x8*)(Alds + base);
            Al[mc] = *(const bf16x8*)(Alds + base + 512);
        }
#pragma unroll
        for (int nc = 0; nc < 4; nc++) {
            int base = ((ng + nc) * 8 + quad) * 128 + l15 * 8;
            Bh[nc] = *(const bf16x8*)(Blds + base);
            Bl[nc] = *(const bf16x8*)(Blds + base + 512);
        }
#pragma unroll
        for (int mc = 0; mc < 4; mc++)
#pragma unroll
            for (int nc = 0; nc < 4; nc++) {
                f32x4 c = acc[mc][nc];
                c = __builtin_amdgcn_mfma_f32_16x16x32_bf16(Ah[mc], Bh[nc], c, 0, 0, 0);
                c = __builtin_amdgcn_mfma_f32_16x16x32_bf16(Ah[mc], Bl[nc], c, 0, 0, 0);
                c = __builtin_amdgcn_mfma_f32_16x16x32_bf16(Al[mc], Bh[nc], c, 0, 0, 0);
                acc[mc][nc] = c;
            }
    }

    // ---- epilogue: bias + RoPE + hi/lo split + swizzled scatter ----
    const int n0w = n0b + (wave & 1) * 64;
    const int m0w = m0 + (wave >> 1) * 64;
    const int sec = n0w >> 10;
    const int h   = (n0w & 1023) >> 6;
    const int bq  = m0w >> 11;
    const size_t abase = (size_t)(bq * NHH + h) * 262144;
    unsigned short* dst = (sec == 0) ? Qg : (sec == 1) ? Kg : Vg;

    float bn[4];
#pragma unroll
    for (int nc = 0; nc < 4; nc++) bn[nc] = bias[n0w + nc * 16 + l15];

    if (sec < 2) {
        // Q gets 0.125 * log2(e) so attention softmax can use exp2 directly
        const float scq = (sec == 0) ? 0.18033688f : 1.0f;
#pragma unroll
        for (int mc = 0; mc < 4; mc++) {
            int sb = (m0w & 2047) + mc * 16;
#pragma unroll
            for (int nc = 0; nc < 4; nc++) {
                int d = nc * 16 + l15;
                int p = d >> 1;
                int kc = d >> 5, quad_a = (d >> 3) & 3, j = d & 7;
#pragma unroll
                for (int rr = 0; rr < 4; rr++) {
                    int srow = sb + quad * 4 + rr;
                    float x = acc[mc][nc][rr] + bn[nc];
                    float xp = __shfl_xor(x, 1);
                    float c = ct[srow * 32 + p], sn = st[srow * 32 + p];
                    float o = ((l15 & 1) == 0) ? (x * c - xp * sn) : (xp * sn + x * c);
                    o *= scq;
                    unsigned int packed = split_pack(o);   // hi | lo<<16
                    unsigned int pp = (unsigned)__shfl_xor((int)packed, 1);
                    if ((l15 & 1) == 0) {
                        unsigned int hw = (packed & 0xffffu) | (pp << 16);
                        unsigned int lw = (packed >> 16) | (pp & 0xffff0000u);
                        size_t e = abase +
                            (size_t)((((srow >> 4) * 2 + kc) * 4 + quad_a) * 2) * 128 +
                            (srow & 15) * 8 + j;
                        *(unsigned int*)(dst + e)       = hw;
                        *(unsigned int*)(dst + e + 128) = lw;
                    }
                }
            }
        }
    } else {
#pragma unroll
        for (int mc = 0; mc < 4; mc++) {
            int sb = (m0w & 2047) + mc * 16;
            int s32 = sb >> 5;
            int quad_v = ((sb >> 3) + (quad >> 1)) & 3;
            int j0 = (quad & 1) * 4;
#pragma unroll
            for (int nc = 0; nc < 4; nc++) {
                float x0 = acc[mc][nc][0] + bn[nc];
                float x1 = acc[mc][nc][1] + bn[nc];
                float x2 = acc[mc][nc][2] + bn[nc];
                float x3 = acc[mc][nc][3] + bn[nc];
                unsigned h01 = pk_hi(x0, x1), h23 = pk_hi(x2, x3);
                unsigned l01 = pk_hi(x0 - hi_trunc(x0), x1 - hi_trunc(x1));
                unsigned l23 = pk_hi(x2 - hi_trunc(x2), x3 - hi_trunc(x3));
                size_t e = abase +
                    (size_t)(((s32 * 4 + nc) * 4 + quad_v) * 2) * 128 + l15 * 8 + j0;
                *(uint2*)(dst + e)       = make_uint2(h01, h23);
                *(uint2*)(dst + e + 128) = make_uint2(l01, l23);
            }
        }
    }
}

// ---------------- kernel 3: flash attention, split-bf16 MFMA --------------
// K/V tile kt+1 is register-prefetched during compute of tile kt, so the
// barrier-to-barrier staging section is pure LDS writes (no global latency).
__global__ __launch_bounds__(256, 2) void attn_mfma_k(
    const unsigned short* __restrict__ Qg,
    const unsigned short* __restrict__ Kg,
    const unsigned short* __restrict__ Vg,
    float* __restrict__ out)
{
    __shared__ __align__(16) unsigned short Klds[8192];
    __shared__ __align__(16) unsigned short Vlds[8192];
    __shared__ __align__(16) unsigned short Pbuf[4][2176];

    const int tid  = threadIdx.x;
    const int wave = tid >> 6;
    const int lane = tid & 63;
    const int quad = lane >> 4;
    const int l15  = lane & 15;
    const int bh   = blockIdx.y;
    const int b    = bh >> 4, h = bh & 15;
    const int q_wave = blockIdx.x * 128 + wave * 32;
    const size_t abase = (size_t)bh * 262144;

    bf16x8 qf[2][2][2];
#pragma unroll
    for (int nc = 0; nc < 2; nc++)
#pragma unroll
        for (int kc = 0; kc < 2; kc++) {
            size_t off = abase +
                (size_t)(((((q_wave >> 4) + nc) * 2 + kc) * 4 + quad) * 2) * 128 + l15 * 8;
            qf[nc][kc][0] = *(const bf16x8*)(Qg + off);
            qf[nc][kc][1] = *(const bf16x8*)(Qg + off + 128);
        }

    f32x4 acc[2][4];
#pragma unroll
    for (int nc = 0; nc < 2; nc++)
#pragma unroll
        for (int dc = 0; dc < 4; dc++) acc[nc][dc] = (f32x4){0.f, 0.f, 0.f, 0.f};
    float mst[2] = {-INFINITY, -INFINITY};
    float lst[2] = {0.f, 0.f};

    const unsigned short* kgb = Kg + abase;
    const unsigned short* vgb = Vg + abase;

    // prefetch tile 0 into registers
    float4 pre[8];
#pragma unroll
    for (int i = 0; i < 4; i++) {
        pre[i]     = *(const float4*)(kgb + (size_t)(tid + i * 256) * 8);
        pre[4 + i] = *(const float4*)(vgb + (size_t)(tid + i * 256) * 8);
    }

    for (int kt = 0; kt < SS / 64; kt++) {
        __syncthreads();
#pragma unroll
        for (int i = 0; i < 4; i++) {
            *(float4*)(Klds + (tid + i * 256) * 8) = pre[i];
            *(float4*)(Vlds + (tid + i * 256) * 8) = pre[4 + i];
        }
        __syncthreads();

        // issue prefetch for kt+1; latency hidden by the MFMA/softmax below
        if (kt < SS / 64 - 1) {
            const unsigned short* kg = kgb + (size_t)(kt + 1) * 8192;
            const unsigned short* vg = vgb + (size_t)(kt + 1) * 8192;
#pragma unroll
            for (int i = 0; i < 4; i++) {
                pre[i]     = *(const float4*)(kg + (size_t)(tid + i * 256) * 8);
                pre[4 + i] = *(const float4*)(vg + (size_t)(tid + i * 256) * 8);
            }
        }

        // ---- QK^T (transposed: St[key][q]), scores already in log2 domain ----
        f32x4 stt[2][4];
#pragma unroll
        for (int mc = 0; mc < 4; mc++) {
            int off0 = ((mc * 2 + 0) * 4 + quad) * 256 + l15 * 8;
            int off1 = ((mc * 2 + 1) * 4 + quad) * 256 + l15 * 8;
            bf16x8 ah0 = *(const bf16x8*)(Klds + off0);
            bf16x8 ah1 = *(const bf16x8*)(Klds + off1);
            bf16x8 al0 = *(const bf16x8*)(Klds + off0 + 128);
            bf16x8 al1 = *(const bf16x8*)(Klds + off1 + 128);
#pragma unroll
            for (int nc = 0; nc < 2; nc++) {
                f32x4 s = (f32x4){0.f, 0.f, 0.f, 0.f};
                s = __builtin_amdgcn_mfma_f32_16x16x32_bf16(ah0, qf[nc][0][0], s, 0, 0, 0);
                s = __builtin_amdgcn_mfma_f32_16x16x32_bf16(ah1, qf[nc][1][0], s, 0, 0, 0);
                s = __builtin_amdgcn_mfma_f32_16x16x32_bf16(ah0, qf[nc][0][1], s, 0, 0, 0);
                s = __builtin_amdgcn_mfma_f32_16x16x32_bf16(ah1, qf[nc][1][1], s, 0, 0, 0);
                s = __builtin_amdgcn_mfma_f32_16x16x32_bf16(al0, qf[nc][0][0], s, 0, 0, 0);
                s = __builtin_amdgcn_mfma_f32_16x16x32_bf16(al1, qf[nc][1][0], s, 0, 0, 0);
                stt[nc][mc] = s;
            }
        }

        bf16x8 vf[4][2][2];
#pragma unroll
        for (int dc = 0; dc < 4; dc++)
#pragma unroll
            for (int kk2 = 0; kk2 < 2; kk2++) {
                int off = ((kk2 * 4 + dc) * 4 + quad) * 256 + l15 * 8;
                vf[dc][kk2][0] = *(const bf16x8*)(Vlds + off);
                vf[dc][kk2][1] = *(const bf16x8*)(Vlds + off + 128);
            }

#pragma unroll
        for (int nc = 0; nc < 2; nc++) {
            float mt = -INFINITY;
#pragma unroll
            for (int mc = 0; mc < 4; mc++)
#pragma unroll
                for (int rr = 0; rr < 4; rr++) mt = fmaxf(mt, stt[nc][mc][rr]);
            mt = fmaxf(mt, __shfl_xor(mt, 16));
            mt = fmaxf(mt, __shfl_xor(mt, 32));
            float mnew = fmaxf(mst[nc], mt);
            float alpha = __builtin_amdgcn_exp2f(mst[nc] - mnew);
            float p[4][4];
            float ps = 0.f;
#pragma unroll
            for (int mc = 0; mc < 4; mc++)
#pragma unroll
                for (int rr = 0; rr < 4; rr++) {
                    float e = __builtin_amdgcn_exp2f(stt[nc][mc][rr] - mnew);
                    p[mc][rr] = e;
                    ps += e;
                }
            ps += __shfl_xor(ps, 16);
            ps += __shfl_xor(ps, 32);
            lst[nc] = lst[nc] * alpha + ps;
            mst[nc] = mnew;

            float ar[4];
#pragma unroll
            for (int rr = 0; rr < 4; rr++)
                ar[rr] = __shfl(alpha, (lane & 48) + ((lane >> 4) << 2) + rr);
#pragma unroll
            for (int dc = 0; dc < 4; dc++)
#pragma unroll
                for (int rr = 0; rr < 4; rr++) acc[nc][dc][rr] *= ar[rr];

            // pack P hi/lo (perm-packed RTZ), LDS round-trip into A-operand layout
            unsigned short* Pw = Pbuf[wave];
#pragma unroll
            for (int mc = 0; mc < 4; mc++)
#pragma unroll
                for (int pr = 0; pr < 2; pr++) {
                    float p0f = p[mc][2 * pr], p1f = p[mc][2 * pr + 1];
                    unsigned hw = pk_hi(p0f, p1f);
                    unsigned lw = pk_hi(p0f - hi_trunc(p0f), p1f - hi_trunc(p1f));
                    int kk2 = mc >> 1;
                    int quadp = (mc & 1) * 2 + (quad >> 1);
                    int j = (quad & 1) * 4 + 2 * pr;
                    int off = (kk2 * 4 + quadp) * 136 + l15 * 8 + j;
                    *(unsigned int*)(Pw + off)        = hw;
                    *(unsigned int*)(Pw + 1088 + off) = lw;
                }
            bf16x8 pf[2][2];
#pragma unroll
            for (int kk2 = 0; kk2 < 2; kk2++) {
                int off = (kk2 * 4 + quad) * 136 + l15 * 8;
                pf[kk2][0] = *(const bf16x8*)(Pw + off);
                pf[kk2][1] = *(const bf16x8*)(Pw + 1088 + off);
            }

#pragma unroll
            for (int dc = 0; dc < 4; dc++) {
                f32x4 aa = acc[nc][dc];
#pragma unroll
                for (int kk2 = 0; kk2 < 2; kk2++) {
                    aa = __builtin_amdgcn_mfma_f32_16x16x32_bf16(pf[kk2][0], vf[dc][kk2][0], aa, 0, 0, 0);
                    aa = __builtin_amdgcn_mfma_f32_16x16x32_bf16(pf[kk2][1], vf[dc][kk2][0], aa, 0, 0, 0);
                    aa = __builtin_amdgcn_mfma_f32_16x16x32_bf16(pf[kk2][0], vf[dc][kk2][1], aa, 0, 0, 0);
                }
                acc[nc][dc] = aa;
            }
        }
    }

#pragma unroll
    for (int nc = 0; nc < 2; nc++) {
        float linv = 1.f / lst[nc];
        float lr[4];
#pragma unroll
        for (int rr = 0; rr < 4; rr++)
            lr[rr] = __shfl(linv, (lane & 48) + ((lane >> 4) << 2) + rr);
#pragma unroll
        for (int dc = 0; dc < 4; dc++)
#pragma unroll
            for (int rr = 0; rr < 4; rr++) {
                int s = q_wave + nc * 16 + quad * 4 + rr;
                out[((size_t)(b * SS + s)) * EE + h * HD + dc * 16 + l15] = acc[nc][dc][rr] * lr[rr];
            }
    }
}

extern "C" void kernel_launch(void* const* d_in, const int* in_sizes, int n_in,
                              void* d_out, int out_size, void* d_ws, size_t ws_size,
                              hipStream_t stream) {
    const float* X    = (const float*)d_in[0];
    const float* W    = (const float*)d_in[1];
    const float* bias = (const float*)d_in[2];
    float* out = (float*)d_out;

    float* ws = (float*)d_ws;
    float* ct = ws;                    // 65536 f32
    float* st = ws + 65536;            // 65536 f32
    unsigned short* base = (unsigned short*)(ws + 131072);
    const size_t ASZ = (size_t)32 * 262144;   // 8.39M bf16 per array (hi/lo interleaved)
    unsigned short* Qg = base;
    unsigned short* Kg = base + ASZ;
    unsigned short* Vg = base + 2 * ASZ;

    rope_table_k<<<(SS * HD2 + 255) / 256, 256, 0, stream>>>(ct, st);
    qkv_mfma_k<<<dim3(3 * EE / 128, BB * SS / 128), 256, 0, stream>>>(
        X, W, bias, ct, st, Qg, Kg, Vg);
    attn_mfma_k<<<dim3(SS / 128, BB * NHH), 256, 0, stream>>>(Qg, Kg, Vg, out);
}

// Round 6
// 286.827 us; speedup vs baseline: 1.2175x; 1.2175x over previous
//
#include <hip/hip_runtime.h>
#include <math.h>

// Problem constants: B=2, S=2048, E=1024, NH=16, hd=64, T=1 (seq = S)
#define BB 2
#define SS 2048
#define EE 1024
#define NHH 16
#define HD 64
#define HD2 32

typedef __attribute__((ext_vector_type(8))) short bf16x8;   // 8 bf16 = 4 VGPRs
typedef __attribute__((ext_vector_type(4))) float f32x4;    // MFMA accumulator

// ---- cheap split-bf16 helpers (RTZ hi + RTZ lo residual; hi+lo ~ 2^-16 rel) ----
static __device__ __forceinline__ unsigned pk_hi(float a, float b) {
    union { float f; unsigned u; } x, y; x.f = a; y.f = b;
    return __builtin_amdgcn_perm(y.u, x.u, 0x07060302u);
}
static __device__ __forceinline__ float hi_trunc(float a) {
    union { float f; unsigned u; } x; x.f = a; x.u &= 0xffff0000u;
    return x.f;
}
static __device__ __forceinline__ unsigned split_pack(float o) {
    return pk_hi(o, o - hi_trunc(o));
}

// ---- async global->LDS DMA, 16B per lane (global_load_lds_dwordx4) ----
// LDS dest must be wave-uniform base + lane*16; our staging layout satisfies
// this (tid*16B contiguous per wave). Completion tracked by vmcnt; the
// compiler's __syncthreads drains vmcnt(0) before s_barrier.
static __device__ __forceinline__ void dma16(const void* g, void* l) {
    __builtin_amdgcn_global_load_lds(
        (const __attribute__((address_space(1))) unsigned int*)g,
        (__attribute__((address_space(3))) unsigned int*)l,
        16, 0, 0);
}

// ---------------- kernel 1: RoPE cos/sin tables ----------------
__global__ __launch_bounds__(256) void rope_table_k(float* __restrict__ ct,
                                                    float* __restrict__ st) {
    int idx = blockIdx.x * 256 + threadIdx.x;   // idx = s*32 + p
    if (idx >= SS * HD2) return;
    int s = idx >> 5, p = idx & 31;
    double inv = pow(10000.0, -(double)(2 * p) / 64.0);
    double ang = (double)s * inv;
    ct[idx] = (float)cos(ang);
    st[idx] = (float)sin(ang);
}

// ---------------- kernel 2: QKV GEMM (split-bf16 MFMA) + bias + RoPE ------
// C = X @ W^T + bias. 128x128 tile, BK=32, 4 waves each 64x64 (4x4 of 16x16).
// Q is pre-scaled by 0.125*log2(e) so attention can use exp2 directly.
__global__ __launch_bounds__(256, 3) void qkv_mfma_k(
    const float* __restrict__ X, const float* __restrict__ W,
    const float* __restrict__ bias,
    const float* __restrict__ ct, const float* __restrict__ st,
    unsigned short* __restrict__ Qg, unsigned short* __restrict__ Kg,
    unsigned short* __restrict__ Vg)
{
    __shared__ __align__(16) unsigned short Alds[8192];   // 16 KB
    __shared__ __align__(16) unsigned short Blds[8192];   // 16 KB

    const int tid  = threadIdx.x;
    const int wave = tid >> 6;
    const int lane = tid & 63;
    const int quad = lane >> 4;
    const int l15  = lane & 15;
    const int m0   = blockIdx.y * 128;
    const int n0b  = blockIdx.x * 128;

    const int r  = tid >> 1;
    const int ks = (tid & 1) * 16;
    const int q0s = ks >> 3;
    const int grp_s = r >> 4;
    const int l15s  = r & 15;

    const float* ap = X + (size_t)(m0 + r) * EE + ks;
    const float* bp = W + (size_t)(n0b + r) * EE + ks;

    f32x4 acc[4][4];
#pragma unroll
    for (int mc = 0; mc < 4; mc++)
#pragma unroll
        for (int nc = 0; nc < 4; nc++) acc[mc][nc] = (f32x4){0.f, 0.f, 0.f, 0.f};

    float4 a[4], bb[4];
#pragma unroll
    for (int i = 0; i < 4; i++) {
        a[i]  = *(const float4*)(ap + i * 4);
        bb[i] = *(const float4*)(bp + i * 4);
    }

    const int mg = (wave >> 1) * 4;
    const int ng = (wave & 1) * 4;

    for (int kt = 0; kt < EE / 32; kt++) {
        __syncthreads();
        // ---- convert (RTZ hi/lo, perm-packed) + write staged tile ----
#pragma unroll
        for (int half = 0; half < 2; half++) {
            int q = q0s + half;
            const float* fa = (const float*)&a[half * 2];
            const float* fb = (const float*)&bb[half * 2];
            unsigned hia[4], loa[4], hib[4], lob[4];
#pragma unroll
            for (int jj = 0; jj < 4; jj++) {
                float pa0 = fa[2 * jj], pa1 = fa[2 * jj + 1];
                hia[jj] = pk_hi(pa0, pa1);
                loa[jj] = pk_hi(pa0 - hi_trunc(pa0), pa1 - hi_trunc(pa1));
                float pb0 = fb[2 * jj], pb1 = fb[2 * jj + 1];
                hib[jj] = pk_hi(pb0, pb1);
                lob[jj] = pk_hi(pb0 - hi_trunc(pb0), pb1 - hi_trunc(pb1));
            }
            int ehi = ((grp_s * 2 + 0) * 4 + q) * 128 + l15s * 8;
            int elo = ((grp_s * 2 + 1) * 4 + q) * 128 + l15s * 8;
            *(uint4*)(Alds + ehi) = make_uint4(hia[0], hia[1], hia[2], hia[3]);
            *(uint4*)(Alds + elo) = make_uint4(loa[0], loa[1], loa[2], loa[3]);
            *(uint4*)(Blds + ehi) = make_uint4(hib[0], hib[1], hib[2], hib[3]);
            *(uint4*)(Blds + elo) = make_uint4(lob[0], lob[1], lob[2], lob[3]);
        }
        __syncthreads();

        if (kt < EE / 32 - 1) {
            ap += 32; bp += 32;
#pragma unroll
            for (int i = 0; i < 4; i++) {
                a[i]  = *(const float4*)(ap + i * 4);
                bb[i] = *(const float4*)(bp + i * 4);
            }
        }

        bf16x8 Ah[4], Al[4], Bh[4], Bl[4];
#pragma unroll
        for (int mc = 0; mc < 4; mc++) {
            int base = ((mg + mc) * 8 + quad) * 128 + l15 * 8;
            Ah[mc] = *(const bf16x8*)(Alds + base);
            Al[mc] = *(const bf16x8*)(Alds + base + 512);
        }
#pragma unroll
        for (int nc = 0; nc < 4; nc++) {
            int base = ((ng + nc) * 8 + quad) * 128 + l15 * 8;
            Bh[nc] = *(const bf16x8*)(Blds + base);
            Bl[nc] = *(const bf16x8*)(Blds + base + 512);
        }
#pragma unroll
        for (int mc = 0; mc < 4; mc++)
#pragma unroll
            for (int nc = 0; nc < 4; nc++) {
                f32x4 c = acc[mc][nc];
                c = __builtin_amdgcn_mfma_f32_16x16x32_bf16(Ah[mc], Bh[nc], c, 0, 0, 0);
                c = __builtin_amdgcn_mfma_f32_16x16x32_bf16(Ah[mc], Bl[nc], c, 0, 0, 0);
                c = __builtin_amdgcn_mfma_f32_16x16x32_bf16(Al[mc], Bh[nc], c, 0, 0, 0);
                acc[mc][nc] = c;
            }
    }

    // ---- epilogue: bias + RoPE + hi/lo split + swizzled scatter ----
    const int n0w = n0b + (wave & 1) * 64;
    const int m0w = m0 + (wave >> 1) * 64;
    const int sec = n0w >> 10;
    const int h   = (n0w & 1023) >> 6;
    const int bq  = m0w >> 11;
    const size_t abase = (size_t)(bq * NHH + h) * 262144;
    unsigned short* dst = (sec == 0) ? Qg : (sec == 1) ? Kg : Vg;

    float bn[4];
#pragma unroll
    for (int nc = 0; nc < 4; nc++) bn[nc] = bias[n0w + nc * 16 + l15];

    if (sec < 2) {
        // Q gets 0.125 * log2(e) so attention softmax can use exp2 directly
        const float scq = (sec == 0) ? 0.18033688f : 1.0f;
#pragma unroll
        for (int mc = 0; mc < 4; mc++) {
            int sb = (m0w & 2047) + mc * 16;
#pragma unroll
            for (int nc = 0; nc < 4; nc++) {
                int d = nc * 16 + l15;
                int p = d >> 1;
                int kc = d >> 5, quad_a = (d >> 3) & 3, j = d & 7;
#pragma unroll
                for (int rr = 0; rr < 4; rr++) {
                    int srow = sb + quad * 4 + rr;
                    float x = acc[mc][nc][rr] + bn[nc];
                    float xp = __shfl_xor(x, 1);
                    float c = ct[srow * 32 + p], sn = st[srow * 32 + p];
                    float o = ((l15 & 1) == 0) ? (x * c - xp * sn) : (xp * sn + x * c);
                    o *= scq;
                    unsigned int packed = split_pack(o);   // hi | lo<<16
                    unsigned int pp = (unsigned)__shfl_xor((int)packed, 1);
                    if ((l15 & 1) == 0) {
                        unsigned int hw = (packed & 0xffffu) | (pp << 16);
                        unsigned int lw = (packed >> 16) | (pp & 0xffff0000u);
                        size_t e = abase +
                            (size_t)((((srow >> 4) * 2 + kc) * 4 + quad_a) * 2) * 128 +
                            (srow & 15) * 8 + j;
                        *(unsigned int*)(dst + e)       = hw;
                        *(unsigned int*)(dst + e + 128) = lw;
                    }
                }
            }
        }
    } else {
#pragma unroll
        for (int mc = 0; mc < 4; mc++) {
            int sb = (m0w & 2047) + mc * 16;
            int s32 = sb >> 5;
            int quad_v = ((sb >> 3) + (quad >> 1)) & 3;
            int j0 = (quad & 1) * 4;
#pragma unroll
            for (int nc = 0; nc < 4; nc++) {
                float x0 = acc[mc][nc][0] + bn[nc];
                float x1 = acc[mc][nc][1] + bn[nc];
                float x2 = acc[mc][nc][2] + bn[nc];
                float x3 = acc[mc][nc][3] + bn[nc];
                unsigned h01 = pk_hi(x0, x1), h23 = pk_hi(x2, x3);
                unsigned l01 = pk_hi(x0 - hi_trunc(x0), x1 - hi_trunc(x1));
                unsigned l23 = pk_hi(x2 - hi_trunc(x2), x3 - hi_trunc(x3));
                size_t e = abase +
                    (size_t)(((s32 * 4 + nc) * 4 + quad_v) * 2) * 128 + l15 * 8 + j0;
                *(uint2*)(dst + e)       = make_uint2(h01, h23);
                *(uint2*)(dst + e + 128) = make_uint2(l01, l23);
            }
        }
    }
}

// ---------------- kernel 3: flash attention, split-bf16 MFMA --------------
// K/V staged via global_load_lds DMA (no VGPR residency, no spill risk);
// __syncthreads after issue drains vmcnt(0) before the barrier.
__global__ __launch_bounds__(256, 2) void attn_mfma_k(
    const unsigned short* __restrict__ Qg,
    const unsigned short* __restrict__ Kg,
    const unsigned short* __restrict__ Vg,
    float* __restrict__ out)
{
    __shared__ __align__(16) unsigned short Klds[8192];
    __shared__ __align__(16) unsigned short Vlds[8192];
    __shared__ __align__(16) unsigned short Pbuf[4][2176];

    const int tid  = threadIdx.x;
    const int wave = tid >> 6;
    const int lane = tid & 63;
    const int quad = lane >> 4;
    const int l15  = lane & 15;
    const int bh   = blockIdx.y;
    const int b    = bh >> 4, h = bh & 15;
    const int q_wave = blockIdx.x * 128 + wave * 32;
    const size_t abase = (size_t)bh * 262144;

    bf16x8 qf[2][2][2];
#pragma unroll
    for (int nc = 0; nc < 2; nc++)
#pragma unroll
        for (int kc = 0; kc < 2; kc++) {
            size_t off = abase +
                (size_t)(((((q_wave >> 4) + nc) * 2 + kc) * 4 + quad) * 2) * 128 + l15 * 8;
            qf[nc][kc][0] = *(const bf16x8*)(Qg + off);
            qf[nc][kc][1] = *(const bf16x8*)(Qg + off + 128);
        }

    f32x4 acc[2][4];
#pragma unroll
    for (int nc = 0; nc < 2; nc++)
#pragma unroll
        for (int dc = 0; dc < 4; dc++) acc[nc][dc] = (f32x4){0.f, 0.f, 0.f, 0.f};
    float mst[2] = {-INFINITY, -INFINITY};
    float lst[2] = {0.f, 0.f};

    const unsigned short* kgb = Kg + abase;
    const unsigned short* vgb = Vg + abase;

    for (int kt = 0; kt < SS / 64; kt++) {
        __syncthreads();   // previous tile's LDS reads done
        {
            const unsigned short* kg = kgb + (size_t)kt * 8192;
            const unsigned short* vg = vgb + (size_t)kt * 8192;
#pragma unroll
            for (int i = 0; i < 4; i++) {
                dma16(kg + (size_t)(tid + i * 256) * 8, Klds + (tid + i * 256) * 8);
                dma16(vg + (size_t)(tid + i * 256) * 8, Vlds + (tid + i * 256) * 8);
            }
        }
        __syncthreads();   // drains vmcnt(0) -> DMA data visible

        // ---- QK^T (transposed: St[key][q]), scores already in log2 domain ----
        f32x4 stt[2][4];
#pragma unroll
        for (int mc = 0; mc < 4; mc++) {
            int off0 = ((mc * 2 + 0) * 4 + quad) * 256 + l15 * 8;
            int off1 = ((mc * 2 + 1) * 4 + quad) * 256 + l15 * 8;
            bf16x8 ah0 = *(const bf16x8*)(Klds + off0);
            bf16x8 ah1 = *(const bf16x8*)(Klds + off1);
            bf16x8 al0 = *(const bf16x8*)(Klds + off0 + 128);
            bf16x8 al1 = *(const bf16x8*)(Klds + off1 + 128);
#pragma unroll
            for (int nc = 0; nc < 2; nc++) {
                f32x4 s = (f32x4){0.f, 0.f, 0.f, 0.f};
                s = __builtin_amdgcn_mfma_f32_16x16x32_bf16(ah0, qf[nc][0][0], s, 0, 0, 0);
                s = __builtin_amdgcn_mfma_f32_16x16x32_bf16(ah1, qf[nc][1][0], s, 0, 0, 0);
                s = __builtin_amdgcn_mfma_f32_16x16x32_bf16(ah0, qf[nc][0][1], s, 0, 0, 0);
                s = __builtin_amdgcn_mfma_f32_16x16x32_bf16(ah1, qf[nc][1][1], s, 0, 0, 0);
                s = __builtin_amdgcn_mfma_f32_16x16x32_bf16(al0, qf[nc][0][0], s, 0, 0, 0);
                s = __builtin_amdgcn_mfma_f32_16x16x32_bf16(al1, qf[nc][1][0], s, 0, 0, 0);
                stt[nc][mc] = s;
            }
        }

        bf16x8 vf[4][2][2];
#pragma unroll
        for (int dc = 0; dc < 4; dc++)
#pragma unroll
            for (int kk2 = 0; kk2 < 2; kk2++) {
                int off = ((kk2 * 4 + dc) * 4 + quad) * 256 + l15 * 8;
                vf[dc][kk2][0] = *(const bf16x8*)(Vlds + off);
                vf[dc][kk2][1] = *(const bf16x8*)(Vlds + off + 128);
            }

#pragma unroll
        for (int nc = 0; nc < 2; nc++) {
            float mt = -INFINITY;
#pragma unroll
            for (int mc = 0; mc < 4; mc++)
#pragma unroll
                for (int rr = 0; rr < 4; rr++) mt = fmaxf(mt, stt[nc][mc][rr]);
            mt = fmaxf(mt, __shfl_xor(mt, 16));
            mt = fmaxf(mt, __shfl_xor(mt, 32));
            float mnew = fmaxf(mst[nc], mt);
            float alpha = __builtin_amdgcn_exp2f(mst[nc] - mnew);
            float p[4][4];
            float ps = 0.f;
#pragma unroll
            for (int mc = 0; mc < 4; mc++)
#pragma unroll
                for (int rr = 0; rr < 4; rr++) {
                    float e = __builtin_amdgcn_exp2f(stt[nc][mc][rr] - mnew);
                    p[mc][rr] = e;
                    ps += e;
                }
            ps += __shfl_xor(ps, 16);
            ps += __shfl_xor(ps, 32);
            lst[nc] = lst[nc] * alpha + ps;
            mst[nc] = mnew;

            float ar[4];
#pragma unroll
            for (int rr = 0; rr < 4; rr++)
                ar[rr] = __shfl(alpha, (lane & 48) + ((lane >> 4) << 2) + rr);
#pragma unroll
            for (int dc = 0; dc < 4; dc++)
#pragma unroll
                for (int rr = 0; rr < 4; rr++) acc[nc][dc][rr] *= ar[rr];

            // pack P hi/lo (perm-packed RTZ), LDS round-trip into A-operand layout
            unsigned short* Pw = Pbuf[wave];
#pragma unroll
            for (int mc = 0; mc < 4; mc++)
#pragma unroll
                for (int pr = 0; pr < 2; pr++) {
                    float p0f = p[mc][2 * pr], p1f = p[mc][2 * pr + 1];
                    unsigned hw = pk_hi(p0f, p1f);
                    unsigned lw = pk_hi(p0f - hi_trunc(p0f), p1f - hi_trunc(p1f));
                    int kk2 = mc >> 1;
                    int quadp = (mc & 1) * 2 + (quad >> 1);
                    int j = (quad & 1) * 4 + 2 * pr;
                    int off = (kk2 * 4 + quadp) * 136 + l15 * 8 + j;
                    *(unsigned int*)(Pw + off)        = hw;
                    *(unsigned int*)(Pw + 1088 + off) = lw;
                }
            bf16x8 pf[2][2];
#pragma unroll
            for (int kk2 = 0; kk2 < 2; kk2++) {
                int off = (kk2 * 4 + quad) * 136 + l15 * 8;
                pf[kk2][0] = *(const bf16x8*)(Pw + off);
                pf[kk2][1] = *(const bf16x8*)(Pw + 1088 + off);
            }

#pragma unroll
            for (int dc = 0; dc < 4; dc++) {
                f32x4 aa = acc[nc][dc];
#pragma unroll
                for (int kk2 = 0; kk2 < 2; kk2++) {
                    aa = __builtin_amdgcn_mfma_f32_16x16x32_bf16(pf[kk2][0], vf[dc][kk2][0], aa, 0, 0, 0);
                    aa = __builtin_amdgcn_mfma_f32_16x16x32_bf16(pf[kk2][1], vf[dc][kk2][0], aa, 0, 0, 0);
                    aa = __builtin_amdgcn_mfma_f32_16x16x32_bf16(pf[kk2][0], vf[dc][kk2][1], aa, 0, 0, 0);
                }
                acc[nc][dc] = aa;
            }
        }
    }

#pragma unroll
    for (int nc = 0; nc < 2; nc++) {
        float linv = 1.f / lst[nc];
        float lr[4];
#pragma unroll
        for (int rr = 0; rr < 4; rr++)
            lr[rr] = __shfl(linv, (lane & 48) + ((lane >> 4) << 2) + rr);
#pragma unroll
        for (int dc = 0; dc < 4; dc++)
#pragma unroll
            for (int rr = 0; rr < 4; rr++) {
                int s = q_wave + nc * 16 + quad * 4 + rr;
                out[((size_t)(b * SS + s)) * EE + h * HD + dc * 16 + l15] = acc[nc][dc][rr] * lr[rr];
            }
    }
}

extern "C" void kernel_launch(void* const* d_in, const int* in_sizes, int n_in,
                              void* d_out, int out_size, void* d_ws, size_t ws_size,
                              hipStream_t stream) {
    const float* X    = (const float*)d_in[0];
    const float* W    = (const float*)d_in[1];
    const float* bias = (const float*)d_in[2];
    float* out = (float*)d_out;

    float* ws = (float*)d_ws;
    float* ct = ws;                    // 65536 f32
    float* st = ws + 65536;            // 65536 f32
    unsigned short* base = (unsigned short*)(ws + 131072);
    const size_t ASZ = (size_t)32 * 262144;   // 8.39M bf16 per array (hi/lo interleaved)
    unsigned short* Qg = base;
    unsigned short* Kg = base + ASZ;
    unsigned short* Vg = base + 2 * ASZ;

    rope_table_k<<<(SS * HD2 + 255) / 256, 256, 0, stream>>>(ct, st);
    qkv_mfma_k<<<dim3(3 * EE / 128, BB * SS / 128), 256, 0, stream>>>(
        X, W, bias, ct, st, Qg, Kg, Vg);
    attn_mfma_k<<<dim3(SS / 128, BB * NHH), 256, 0, stream>>>(Qg, Kg, Vg, out);
}